// Round 8
// baseline (63.260 us; speedup 1.0000x reference)
//
#include <hip/hip_runtime.h>
#include <math.h>

#define N_ROWS 1024
#define RANK   8
#define M_COLS 4096

#define R_ROWS   2      // n-rows per thread (Hft load shared across rows)
#define T_PTS    8      // m-points per thread (trig amortized by rotation)
#define M_STRIDE 512    // point spacing (coalesced loads/stores)

// Static device scratch (fully overwritten every call before read).
__device__ float  g_Wp [N_ROWS * RANK];   // softplus(W), 32 KB
__device__ float2 g_Hft[RANK * M_COLS];   // full FFT of softplus(H), 256 KB

// fast softplus: 2 trans + ~4 VALU. exact for x>20; inputs are ~N(0,1).
__device__ __forceinline__ float softplus_f(float x) {
    float t = __expf(x);
    float r = 0.69314718056f * __log2f(1.0f + t);
    return (x > 20.0f) ? x : r;
}
// hw trig: v_sin/v_cos compute sin/cos(2*pi*x), x in revolutions.
__device__ __forceinline__ float sin_rev(float x) { return __builtin_amdgcn_sinf(x); }
__device__ __forceinline__ float cos_rev(float x) { return __builtin_amdgcn_cosf(x); }
__device__ __forceinline__ float fract_f(float x) { return __builtin_amdgcn_fractf(x); }

// ---------------------------------------------------------------------------
// Fused FFT: softplus(H) + 64x64 Cooley-Tukey DFT -> g_Hft.
// 128 blocks x 256 threads; block b: d = b>>4, m0 range [(b&15)*4, +4).
// ---------------------------------------------------------------------------
__global__ void fft_fused(const float* __restrict__ H,
                          const float* __restrict__ W) {
    __shared__ float  sHs[M_COLS];        // 16 KB
    __shared__ float2 sY[4 * 64];         // [j][k0], 2 KB

    int tid = threadIdx.x;
    int d   = blockIdx.x >> 4;
    int m0b = (blockIdx.x & 15) << 2;

    if (blockIdx.x < 32) {                // Wp side-job (no dependency)
        int t = blockIdx.x * 256 + tid;   // < 8192
        g_Wp[t] = softplus_f(W[t]);
    }

    const float4* Hrow4 = (const float4*)(H + d * M_COLS);
    #pragma unroll
    for (int p = 0; p < 4; ++p) {
        int i = p * 256 + tid;            // 1024 float4 per row
        float4 h4 = Hrow4[i];
        sHs[i*4+0] = softplus_f(h4.x);
        sHs[i*4+1] = softplus_f(h4.y);
        sHs[i*4+2] = softplus_f(h4.z);
        sHs[i*4+3] = softplus_f(h4.w);
    }
    __syncthreads();

    {   // stage A: thread = (k0 = tid&63, j = tid>>6), m0 = m0b + j
        int k0 = tid & 63, j = tid >> 6;
        int m0 = m0b + j;
        float mrev = (float)m0 * (1.0f / 64.0f);
        float rr =  cos_rev(mrev);
        float ri = -sin_rev(mrev);        // step = e^{-2pi i m0/64}
        float twr = 1.0f, twi = 0.0f;
        float ar = 0.0f, ai = 0.0f;
        #pragma unroll
        for (int k1 = 0; k1 < 64; ++k1) {
            float v = sHs[(k1 << 6) + k0];
            ar = fmaf(v, twr, ar);
            ai = fmaf(v, twi, ai);
            float nr = fmaf(twr, rr, -(twi * ri));
            twi      = fmaf(twr, ri,   twi * rr);
            twr = nr;
        }
        sY[(j << 6) + k0] = make_float2(ar, ai);
    }
    __syncthreads();

    {   // stage B: thread = (m1 = tid&63, j = tid>>6), m = m1*64 + m0b + j
        int m1 = tid & 63, j = tid >> 6;
        int m  = (m1 << 6) + m0b + j;
        float mrev = (float)m * (1.0f / 4096.0f);
        float rr =  cos_rev(mrev);
        float ri = -sin_rev(mrev);        // step = e^{-2pi i m/4096}
        float twr = 1.0f, twi = 0.0f;
        float ar = 0.0f, ai = 0.0f;
        #pragma unroll
        for (int k0 = 0; k0 < 64; ++k0) {
            float2 y = sY[(j << 6) + k0];
            ar = fmaf(y.x, twr, fmaf(-y.y, twi, ar));
            ai = fmaf(y.x, twi, fmaf( y.y, twr, ai));
            float nr = fmaf(twr, rr, -(twi * ri));
            twi      = fmaf(twr, ri,   twi * rr);
            twr = nr;
        }
        g_Hft[d * M_COLS + m] = make_float2(ar, ai);
    }
}

// ---------------------------------------------------------------------------
// Main: Re(V)[n,m] = sum_d Wp * ( cos(2pi r)*hr + sin(2pi r)*hi ), r = tau*m/M.
// j-OUTER / d-INNER: 16 independent phasor chains (uw[r][d]) -> ILP ~16,
// rotation latency hidden in-order. grid (2,512) = 4 waves/SIMD, VGPR < 128.
// ---------------------------------------------------------------------------
__global__ void shiftnmf_main(const float* __restrict__ tau,
                              float* __restrict__ out) {
    int tid = threadIdx.x;
    int m0  = blockIdx.x * 256 + tid;     // 0..511
    int n0  = blockIdx.y * R_ROWS;

    float fm0 = (float)m0 * (1.0f / (float)M_COLS);

    // phasor state + per-d step rotation, all resident
    float uwr[R_ROWS][RANK], uwi[R_ROWS][RANK];
    float vr [R_ROWS][RANK], vi [R_ROWS][RANK];
    #pragma unroll
    for (int r = 0; r < R_ROWS; ++r) {
        int n = n0 + r;
        #pragma unroll
        for (int d = 0; d < RANK; ++d) {
            float w  = g_Wp[n * RANK + d];            // block-uniform -> s_load
            float tv = tau [n * RANK + d];            // block-uniform -> s_load
            float sv = fract_f(tv * (1.0f / 8.0f));   // 512/4096
            vr[r][d] = cos_rev(sv);                   // step = e^{+i 2pi tau*512/M}
            vi[r][d] = sin_rev(sv);
            float r0 = fract_f(tv * fm0);
            float c0 = cos_rev(r0), s0 = sin_rev(r0);
            uwr[r][d] = w * c0;                       // uw = w * e^{+i 2pi tau*m0/M}
            uwi[r][d] = w * s0;
        }
    }

    float acc[R_ROWS][T_PTS];
    #pragma unroll
    for (int j = 0; j < T_PTS; ++j) {
        float2 h[RANK];
        #pragma unroll
        for (int d = 0; d < RANK; ++d)                // 8 independent L2 loads
            h[d] = g_Hft[d * M_COLS + m0 + j * M_STRIDE];

        #pragma unroll
        for (int r = 0; r < R_ROWS; ++r) {
            float a = 0.0f;
            #pragma unroll
            for (int d = 0; d < RANK; ++d)
                a = fmaf(uwr[r][d], h[d].x, fmaf(uwi[r][d], h[d].y, a));
            acc[r][j] = a;
        }
        if (j < T_PTS - 1) {                          // advance 16 indep phasors
            #pragma unroll
            for (int r = 0; r < R_ROWS; ++r)
                #pragma unroll
                for (int d = 0; d < RANK; ++d) {
                    float nr  = fmaf(uwr[r][d], vr[r][d], -(uwi[r][d] * vi[r][d]));
                    uwi[r][d] = fmaf(uwr[r][d], vi[r][d],   uwi[r][d] * vr[r][d]);
                    uwr[r][d] = nr;
                }
        }
    }

    #pragma unroll
    for (int r = 0; r < R_ROWS; ++r) {
        float* op = out + (n0 + r) * M_COLS + m0;
        #pragma unroll
        for (int j = 0; j < T_PTS; ++j)
            op[j * M_STRIDE] = acc[r][j];
    }
}

extern "C" void kernel_launch(void* const* d_in, const int* in_sizes, int n_in,
                              void* d_out, int out_size, void* d_ws, size_t ws_size,
                              hipStream_t stream) {
    const float* W   = (const float*)d_in[0];   // [1024, 8]
    const float* H   = (const float*)d_in[1];   // [8, 4096]
    const float* tau = (const float*)d_in[2];   // [1024, 8]

    fft_fused<<<dim3(RANK * 16), dim3(256), 0, stream>>>(H, W);

    dim3 grid(M_COLS / (256 * T_PTS), N_ROWS / R_ROWS);  // (2, 512)
    shiftnmf_main<<<grid, dim3(256), 0, stream>>>(tau, (float*)d_out);
}

// Round 9
// 31.239 us; speedup vs baseline: 2.0250x; 2.0250x over previous
//
#include <hip/hip_runtime.h>
#include <math.h>

#define N_ROWS 1024
#define RANK   8
#define M_COLS 4096

#define R_ROWS 2        // n-rows per thread
#define T_PTS  8        // CONTIGUOUS m-points per thread (float4 loads/stores)

// Static device scratch (fully overwritten every call before read).
__device__ float g_Wp[N_ROWS * RANK];                     // softplus(W), 32 KB
__device__ __align__(16) float2 g_Hft[RANK * M_COLS];     // FFT(softplus(H)), 256 KB

// fast softplus: 2 trans + ~4 VALU. exact for x>20; inputs are ~N(0,1).
__device__ __forceinline__ float softplus_f(float x) {
    float t = __expf(x);
    float r = 0.69314718056f * __log2f(1.0f + t);
    return (x > 20.0f) ? x : r;
}
// hw trig: v_sin/v_cos compute sin/cos(2*pi*x), x in revolutions.
__device__ __forceinline__ float sin_rev(float x) { return __builtin_amdgcn_sinf(x); }
__device__ __forceinline__ float cos_rev(float x) { return __builtin_amdgcn_cosf(x); }
__device__ __forceinline__ float fract_f(float x) { return __builtin_amdgcn_fractf(x); }

// ---------------------------------------------------------------------------
// Fused FFT: softplus(H) + 64x64 Cooley-Tukey DFT -> g_Hft.
// 128 blocks x 256 threads; block b: d = b>>4, m0 range [(b&15)*4, +4).
// ---------------------------------------------------------------------------
__global__ void fft_fused(const float* __restrict__ H,
                          const float* __restrict__ W) {
    __shared__ float  sHs[M_COLS];        // 16 KB
    __shared__ float2 sY[4 * 64];         // [j][k0], 2 KB

    int tid = threadIdx.x;
    int d   = blockIdx.x >> 4;
    int m0b = (blockIdx.x & 15) << 2;

    if (blockIdx.x < 32) {                // Wp side-job (no dependency)
        int t = blockIdx.x * 256 + tid;   // < 8192
        g_Wp[t] = softplus_f(W[t]);
    }

    const float4* Hrow4 = (const float4*)(H + d * M_COLS);
    #pragma unroll
    for (int p = 0; p < 4; ++p) {
        int i = p * 256 + tid;            // 1024 float4 per row
        float4 h4 = Hrow4[i];
        sHs[i*4+0] = softplus_f(h4.x);
        sHs[i*4+1] = softplus_f(h4.y);
        sHs[i*4+2] = softplus_f(h4.z);
        sHs[i*4+3] = softplus_f(h4.w);
    }
    __syncthreads();

    {   // stage A: thread = (k0 = tid&63, j = tid>>6), m0 = m0b + j
        int k0 = tid & 63, j = tid >> 6;
        int m0 = m0b + j;
        float mrev = (float)m0 * (1.0f / 64.0f);
        float rr =  cos_rev(mrev);
        float ri = -sin_rev(mrev);        // step = e^{-2pi i m0/64}
        float twr = 1.0f, twi = 0.0f;
        float ar = 0.0f, ai = 0.0f;
        #pragma unroll
        for (int k1 = 0; k1 < 64; ++k1) {
            float v = sHs[(k1 << 6) + k0];
            ar = fmaf(v, twr, ar);
            ai = fmaf(v, twi, ai);
            float nr = fmaf(twr, rr, -(twi * ri));
            twi      = fmaf(twr, ri,   twi * rr);
            twr = nr;
        }
        sY[(j << 6) + k0] = make_float2(ar, ai);
    }
    __syncthreads();

    {   // stage B: thread = (m1 = tid&63, j = tid>>6), m = m1*64 + m0b + j
        int m1 = tid & 63, j = tid >> 6;
        int m  = (m1 << 6) + m0b + j;
        float mrev = (float)m * (1.0f / 4096.0f);
        float rr =  cos_rev(mrev);
        float ri = -sin_rev(mrev);        // step = e^{-2pi i m/4096}
        float twr = 1.0f, twi = 0.0f;
        float ar = 0.0f, ai = 0.0f;
        #pragma unroll
        for (int k0 = 0; k0 < 64; ++k0) {
            float2 y = sY[(j << 6) + k0];
            ar = fmaf(y.x, twr, fmaf(-y.y, twi, ar));
            ai = fmaf(y.x, twi, fmaf( y.y, twr, ai));
            float nr = fmaf(twr, rr, -(twi * ri));
            twi      = fmaf(twr, ri,   twi * rr);
            twr = nr;
        }
        g_Hft[d * M_COLS + m] = make_float2(ar, ai);
    }
}

// ---------------------------------------------------------------------------
// Main: Re(V)[n,m] = sum_d Wp * ( cos(2pi r)*hr + sin(2pi r)*hi ), r = tau*m/M.
// d-OUTER (low register pressure, R8 spill lesson) + software-pipelined Hft
// prefetch (d+1 loads issued before d's compute) + contiguous 8-point tiles
// (float4 loads/stores). __launch_bounds__(256,4): VGPR cap 128, no spills,
// 4 waves/SIMD. grid (2,512) = 4096 waves.
// ---------------------------------------------------------------------------
__global__ __launch_bounds__(256, 4)
void shiftnmf_main(const float* __restrict__ tau,
                   float* __restrict__ out) {
    int tid = threadIdx.x;
    int mt  = blockIdx.x * 256 + tid;     // m-thread index 0..511
    int m0  = mt * T_PTS;                 // contiguous 8-point tile base
    int n0  = blockIdx.y * R_ROWS;

    float fm0 = (float)m0 * (1.0f / (float)M_COLS);

    float acc[R_ROWS][T_PTS];
    #pragma unroll
    for (int r = 0; r < R_ROWS; ++r)
        #pragma unroll
        for (int j = 0; j < T_PTS; ++j) acc[r][j] = 0.0f;

    float4 hc[4], hn[4];                  // current / next d-tile (8 float2 each)
    {
        const float4* p = (const float4*)(g_Hft + m0);
        hc[0] = p[0]; hc[1] = p[1]; hc[2] = p[2]; hc[3] = p[3];
    }

    #pragma unroll
    for (int d = 0; d < RANK; ++d) {
        if (d + 1 < RANK) {               // prefetch next d (hides L2 latency)
            const float4* p = (const float4*)(g_Hft + (d + 1) * M_COLS + m0);
            hn[0] = p[0]; hn[1] = p[1]; hn[2] = p[2]; hn[3] = p[3];
        }

        // phasors for this d only (8 regs live)
        float uwr[R_ROWS], uwi[R_ROWS], vr[R_ROWS], vi[R_ROWS];
        #pragma unroll
        for (int r = 0; r < R_ROWS; ++r) {
            int n    = n0 + r;
            float w  = g_Wp[n * RANK + d];            // block-uniform -> s_load
            float tv = tau [n * RANK + d];            // block-uniform -> s_load
            float sv = fract_f(tv * (1.0f / (float)M_COLS));  // step: 1 m-point
            vr[r] = cos_rev(sv);                      // v = e^{+i 2pi tau/M}
            vi[r] = sin_rev(sv);
            float r0 = fract_f(tv * fm0);
            float c0 = cos_rev(r0), s0 = sin_rev(r0);
            uwr[r] = w * c0;                          // uw = w * e^{+i 2pi tau*m0/M}
            uwi[r] = w * s0;
        }

        #pragma unroll
        for (int q = 0; q < 4; ++q) {                 // 2 points per float4
            float hx0 = hc[q].x, hy0 = hc[q].y;
            float hx1 = hc[q].z, hy1 = hc[q].w;
            #pragma unroll
            for (int r = 0; r < R_ROWS; ++r) {
                int j0 = 2 * q;
                acc[r][j0] = fmaf(uwr[r], hx0, fmaf(uwi[r], hy0, acc[r][j0]));
                // advance phasor to point j0+1
                float nr = fmaf(uwr[r], vr[r], -(uwi[r] * vi[r]));
                uwi[r]   = fmaf(uwr[r], vi[r],   uwi[r] * vr[r]);
                uwr[r]   = nr;
                acc[r][j0+1] = fmaf(uwr[r], hx1, fmaf(uwi[r], hy1, acc[r][j0+1]));
                if (q < 3) {                          // advance to next float4
                    float nr2 = fmaf(uwr[r], vr[r], -(uwi[r] * vi[r]));
                    uwi[r]    = fmaf(uwr[r], vi[r],   uwi[r] * vr[r]);
                    uwr[r]    = nr2;
                }
            }
        }

        #pragma unroll
        for (int q = 0; q < 4; ++q) hc[q] = hn[q];    // rotate buffers
    }

    #pragma unroll
    for (int r = 0; r < R_ROWS; ++r) {
        float4* o4 = (float4*)(out + (n0 + r) * M_COLS + m0);
        o4[0] = make_float4(acc[r][0], acc[r][1], acc[r][2], acc[r][3]);
        o4[1] = make_float4(acc[r][4], acc[r][5], acc[r][6], acc[r][7]);
    }
}

extern "C" void kernel_launch(void* const* d_in, const int* in_sizes, int n_in,
                              void* d_out, int out_size, void* d_ws, size_t ws_size,
                              hipStream_t stream) {
    const float* W   = (const float*)d_in[0];   // [1024, 8]
    const float* H   = (const float*)d_in[1];   // [8, 4096]
    const float* tau = (const float*)d_in[2];   // [1024, 8]

    fft_fused<<<dim3(RANK * 16), dim3(256), 0, stream>>>(H, W);

    dim3 grid(M_COLS / (256 * T_PTS), N_ROWS / R_ROWS);  // (2, 512)
    shiftnmf_main<<<grid, dim3(256), 0, stream>>>(tau, (float*)d_out);
}

// Round 10
// 23.499 us; speedup vs baseline: 2.6921x; 1.3294x over previous
//
#include <hip/hip_runtime.h>
#include <math.h>

#define N_ROWS 1024
#define RANK   8
#define M_COLS 4096

#define R_ROWS   2      // n-rows per thread (Hft load shared across rows)
#define T_PTS    4      // m-points per thread (trig amortized by rotation)
#define M_STRIDE 1024   // point spacing (per-lane 8B stride-1 => coalesced)

// Static device scratch (fully overwritten every call before read).
__device__ float  g_Wp [N_ROWS * RANK];   // softplus(W), 32 KB
__device__ float2 g_Hft[RANK * M_COLS];   // full FFT of softplus(H), 256 KB

// fast softplus: 2 trans + ~4 VALU. exact for x>20; inputs are ~N(0,1).
__device__ __forceinline__ float softplus_f(float x) {
    float t = __expf(x);
    float r = 0.69314718056f * __log2f(1.0f + t);
    return (x > 20.0f) ? x : r;
}
// hw trig: v_sin/v_cos compute sin/cos(2*pi*x), x in revolutions.
__device__ __forceinline__ float sin_rev(float x) { return __builtin_amdgcn_sinf(x); }
__device__ __forceinline__ float cos_rev(float x) { return __builtin_amdgcn_cosf(x); }
__device__ __forceinline__ float fract_f(float x) { return __builtin_amdgcn_fractf(x); }

// ---------------------------------------------------------------------------
// Fused FFT: softplus(H) + 64x64 Cooley-Tukey DFT -> g_Hft.
// 128 blocks x 256 threads; block b: d = b>>4, m0 range [(b&15)*4, +4).
// (validated structure, unchanged from the 21.2us round)
// ---------------------------------------------------------------------------
__global__ void fft_fused(const float* __restrict__ H,
                          const float* __restrict__ W) {
    __shared__ float  sHs[M_COLS];        // 16 KB
    __shared__ float2 sY[4 * 64];         // [j][k0], 2 KB

    int tid = threadIdx.x;
    int d   = blockIdx.x >> 4;
    int m0b = (blockIdx.x & 15) << 2;

    if (blockIdx.x < 32) {                // Wp side-job (no dependency)
        int t = blockIdx.x * 256 + tid;   // < 8192
        g_Wp[t] = softplus_f(W[t]);
    }

    const float4* Hrow4 = (const float4*)(H + d * M_COLS);
    #pragma unroll
    for (int p = 0; p < 4; ++p) {
        int i = p * 256 + tid;            // 1024 float4 per row
        float4 h4 = Hrow4[i];
        sHs[i*4+0] = softplus_f(h4.x);
        sHs[i*4+1] = softplus_f(h4.y);
        sHs[i*4+2] = softplus_f(h4.z);
        sHs[i*4+3] = softplus_f(h4.w);
    }
    __syncthreads();

    {   // stage A: thread = (k0 = tid&63, j = tid>>6), m0 = m0b + j
        int k0 = tid & 63, j = tid >> 6;
        int m0 = m0b + j;
        float mrev = (float)m0 * (1.0f / 64.0f);
        float rr =  cos_rev(mrev);
        float ri = -sin_rev(mrev);        // step = e^{-2pi i m0/64}
        float twr = 1.0f, twi = 0.0f;
        float ar = 0.0f, ai = 0.0f;
        #pragma unroll
        for (int k1 = 0; k1 < 64; ++k1) {
            float v = sHs[(k1 << 6) + k0];
            ar = fmaf(v, twr, ar);
            ai = fmaf(v, twi, ai);
            float nr = fmaf(twr, rr, -(twi * ri));
            twi      = fmaf(twr, ri,   twi * rr);
            twr = nr;
        }
        sY[(j << 6) + k0] = make_float2(ar, ai);
    }
    __syncthreads();

    {   // stage B: thread = (m1 = tid&63, j = tid>>6), m = m1*64 + m0b + j
        int m1 = tid & 63, j = tid >> 6;
        int m  = (m1 << 6) + m0b + j;
        float mrev = (float)m * (1.0f / 4096.0f);
        float rr =  cos_rev(mrev);
        float ri = -sin_rev(mrev);        // step = e^{-2pi i m/4096}
        float twr = 1.0f, twi = 0.0f;
        float ar = 0.0f, ai = 0.0f;
        #pragma unroll
        for (int k0 = 0; k0 < 64; ++k0) {
            float2 y = sY[(j << 6) + k0];
            ar = fmaf(y.x, twr, fmaf(-y.y, twi, ar));
            ai = fmaf(y.x, twi, fmaf( y.y, twr, ai));
            float nr = fmaf(twr, rr, -(twi * ri));
            twi      = fmaf(twr, ri,   twi * rr);
            twr = nr;
        }
        g_Hft[d * M_COLS + m] = make_float2(ar, ai);
    }
}

// ---------------------------------------------------------------------------
// Main: Re(V)[n,m] = sum_d Wp * ( cos(2pi r)*hr + sin(2pi r)*hi ), r = tau*m/M.
// R6-structure (best so far): d-outer, stride-interleaved points, per-lane 8B
// coalesced access, low VGPR. Occupancy raised: T_PTS=4 => grid (4,512) =
// 8192 waves = 8 waves/SIMD (was 4). Dead last rotation skipped.
// ---------------------------------------------------------------------------
__global__ void shiftnmf_main(const float* __restrict__ tau,
                              float* __restrict__ out) {
    int tid = threadIdx.x;
    int m0  = blockIdx.x * 256 + tid;     // 0..1023
    int n0  = blockIdx.y * R_ROWS;

    float acc[R_ROWS][T_PTS];
    #pragma unroll
    for (int r = 0; r < R_ROWS; ++r)
        #pragma unroll
        for (int j = 0; j < T_PTS; ++j) acc[r][j] = 0.0f;

    float fm0 = (float)m0 * (1.0f / (float)M_COLS);

    #pragma unroll
    for (int d = 0; d < RANK; ++d) {
        float uwr[R_ROWS], uwi[R_ROWS], vr[R_ROWS], vi[R_ROWS];
        #pragma unroll
        for (int r = 0; r < R_ROWS; ++r) {
            int n    = n0 + r;
            float w  = g_Wp[n * RANK + d];            // block-uniform -> s_load
            float tv = tau [n * RANK + d];            // block-uniform -> s_load
            float sv = fract_f(tv * ((float)M_STRIDE / (float)M_COLS)); // tv/4
            vr[r] = cos_rev(sv);                      // step = e^{+i 2pi tau*1024/M}
            vi[r] = sin_rev(sv);
            float r0 = fract_f(tv * fm0);
            float c0 = cos_rev(r0), s0 = sin_rev(r0);
            uwr[r] = w * c0;                          // uw = w * e^{+i 2pi tau*m0/M}
            uwi[r] = w * s0;
        }
        const float2* hp = g_Hft + d * M_COLS + m0;
        #pragma unroll
        for (int j = 0; j < T_PTS; ++j) {
            float2 h = hp[j * M_STRIDE];              // coalesced, L2/L1-resident
            #pragma unroll
            for (int r = 0; r < R_ROWS; ++r) {
                acc[r][j] = fmaf(uwr[r], h.x, fmaf(uwi[r], h.y, acc[r][j]));
                if (j < T_PTS - 1) {                  // skip dead final rotation
                    float nr = fmaf(uwr[r], vr[r], -(uwi[r] * vi[r]));  // uw *= v
                    uwi[r]   = fmaf(uwr[r], vi[r],   uwi[r] * vr[r]);
                    uwr[r]   = nr;
                }
            }
        }
    }

    #pragma unroll
    for (int r = 0; r < R_ROWS; ++r) {
        float* op = out + (n0 + r) * M_COLS + m0;
        #pragma unroll
        for (int j = 0; j < T_PTS; ++j)
            op[j * M_STRIDE] = acc[r][j];
    }
}

extern "C" void kernel_launch(void* const* d_in, const int* in_sizes, int n_in,
                              void* d_out, int out_size, void* d_ws, size_t ws_size,
                              hipStream_t stream) {
    const float* W   = (const float*)d_in[0];   // [1024, 8]
    const float* H   = (const float*)d_in[1];   // [8, 4096]
    const float* tau = (const float*)d_in[2];   // [1024, 8]

    fft_fused<<<dim3(RANK * 16), dim3(256), 0, stream>>>(H, W);

    dim3 grid(M_COLS / (256 * T_PTS), N_ROWS / R_ROWS);  // (4, 512) = 8 waves/SIMD
    shiftnmf_main<<<grid, dim3(256), 0, stream>>>(tau, (float*)d_out);
}